// Round 9
// baseline (277.524 us; speedup 1.0000x reference)
//
#include <hip/hip_runtime.h>

// MEASUREMENT ROUND: identical kernel to R6/R7 (passed), launched 5x to
// expose main's true duration via the bench delta: T_main = (dur - 149.5)/4.
//
// Fused: out[i,j] = sum_d x[i,d] * Weff[j,d] + b[j]
// Weff[j,d] = W[j,d] + sum_k M[k,d] * W[j, 42+k]  (M = connect-4 window masks,
// incl. reference bugs: diag windows are full 4x4 blocks; feats 57..68 zero).

#define TILE_F 2688   // 64 rows * 42 floats, LINEAR per-wave LDS tile

__global__ __launch_bounds__(256)
void ddqn_fused(const float* __restrict__ gs,
                const float* __restrict__ W,
                const float* __restrict__ b,
                float* __restrict__ out) {
    __shared__ __align__(16) float wl[7 * 44];      // Weff, rows padded to 44
    __shared__ __align__(16) float tile[4][TILE_F]; // per-wave 64x42 x slabs

    const int t = threadIdx.x;
    const int w = t >> 6;
    const int l = t & 63;
    float* tw = tile[w];

    const size_t tileIdx = (size_t)blockIdx.x * 4 + w;   // 64 rows per wave
    const float* src = gs + tileIdx * TILE_F;

    // ---- Async stage: 10 x b128 (1 KB/instr) + 2 x b32, direct to LDS.
    #pragma unroll
    for (int k = 0; k < 10; ++k) {
        __builtin_amdgcn_global_load_lds(
            (const __attribute__((address_space(1))) void*)(src + k * 256 + l * 4),
            (__attribute__((address_space(3))) void*)(tw + k * 256),
            16, 0, 0);
    }
    #pragma unroll
    for (int m = 0; m < 2; ++m) {
        __builtin_amdgcn_global_load_lds(
            (const __attribute__((address_space(1))) void*)(src + 2560 + m * 64 + l),
            (__attribute__((address_space(3))) void*)(tw + 2560 + m * 64),
            4, 0, 0);
    }

    // ---- Weff recompute (runs while the staging loads are in flight).
    for (int i = t; i < 7 * 44; i += 256) {
        int j = i / 44, d = i - j * 44;
        float acc = 0.0f;
        if (d < 42) {
            acc = W[j * 111 + d];
            int r = d / 7, c = d - r * 7;
            const float* ws = W + j * 111 + 42;
            #pragma unroll
            for (int i4 = 0; i4 < 4; ++i4)          // 24 row windows
                if (c >= i4 && c <= i4 + 3) acc += ws[r * 4 + i4];
            #pragma unroll
            for (int i3 = 0; i3 < 3; ++i3)          // 21 col windows
                if (r >= i3 && r <= i3 + 3) acc += ws[24 + c * 3 + i3];
            #pragma unroll
            for (int off = 0; off < 3; ++off)       // 12 "diag" (full 4x4 bug)
                #pragma unroll
                for (int c4 = 0; c4 < 4; ++c4)
                    if (r >= 2 - off && r <= 5 - off && c >= c4 && c <= c4 + 3)
                        acc += ws[45 + off * 4 + c4];
        }
        wl[i] = acc;                                // feats 57..68: zero masks
    }
    __syncthreads();   // drains vmcnt(0): staged x AND wl both ready

    // ---- Compute: one row per thread.
    float x[44];
    const float* xr = tw + l * 42;
    #pragma unroll
    for (int d = 0; d < 42; ++d) x[d] = xr[d];
    x[42] = x[43] = 0.0f;

    float acc[7];
    #pragma unroll
    for (int j = 0; j < 7; ++j) acc[j] = b[j];      // uniform -> s_load

    const float4* wl4 = (const float4*)wl;
    #pragma unroll
    for (int dq = 0; dq < 11; ++dq) {
        #pragma unroll
        for (int j = 0; j < 7; ++j) {
            const float4 wv = wl4[j * 11 + dq];
            acc[j] = fmaf(x[dq * 4 + 0], wv.x, acc[j]);
            acc[j] = fmaf(x[dq * 4 + 1], wv.y, acc[j]);
            acc[j] = fmaf(x[dq * 4 + 2], wv.z, acc[j]);
            acc[j] = fmaf(x[dq * 4 + 3], wv.w, acc[j]);
        }
    }

    float* o = out + (tileIdx * 64 + l) * 7;
    #pragma unroll
    for (int j = 0; j < 7; ++j) o[j] = acc[j];
}

extern "C" void kernel_launch(void* const* d_in, const int* in_sizes, int n_in,
                              void* d_out, int out_size, void* d_ws, size_t ws_size,
                              hipStream_t stream) {
    const float* gs = (const float*)d_in[0];   // [B, 42] f32
    const float* W  = (const float*)d_in[1];   // [7, 111] f32
    const float* b  = (const float*)d_in[2];   // [7] f32
    float* out = (float*)d_out;                // [B, 7] f32

    int B = in_sizes[0] / 42;                  // 524288
    int tiles = B / 64;                        // 8192 wave-tiles

    // 5 identical launches (idempotent). T_main = (dur_us - 149.5) / 4.
    for (int rep = 0; rep < 5; ++rep)
        ddqn_fused<<<dim3(tiles / 4), dim3(256), 0, stream>>>(gs, W, b, out);
}

// Round 10
// 182.244 us; speedup vs baseline: 1.5228x; 1.5228x over previous
//
#include <hip/hip_runtime.h>

// INSTRUMENTED ROUND: one dispatch runs the full workload nrep=4 times so the
// main kernel finally crosses the profiler's top-5 cut (~52us) and reports its
// own FETCH_SIZE / VALUBusy / Occupancy / LDS_BANK_CONFLICT. Passes are
// idempotent (same stores); global_load_lds has side effects so the compiler
// cannot collapse passes; Weff is computed once before the rep loop.
//
// Fused: out[i,j] = sum_d x[i,d] * Weff[j,d] + b[j]
// Weff[j,d] = W[j,d] + sum_k M[k,d] * W[j, 42+k]  (M = connect-4 window masks,
// incl. reference bugs: diag windows are full 4x4 blocks; feats 57..68 zero).

#define TILE_F 2688   // 64 rows * 42 floats, LINEAR per-wave LDS tile

__global__ __launch_bounds__(256)
void ddqn_fused(const float* __restrict__ gs,
                const float* __restrict__ W,
                const float* __restrict__ b,
                float* __restrict__ out,
                int nrep) {
    __shared__ __align__(16) float wl[7 * 44];      // Weff, rows padded to 44
    __shared__ __align__(16) float tile[4][TILE_F]; // per-wave 64x42 x slabs

    const int t = threadIdx.x;
    const int w = t >> 6;
    const int l = t & 63;
    float* tw = tile[w];

    const size_t tileIdx = (size_t)blockIdx.x * 4 + w;   // 64 rows per wave
    const float* src = gs + tileIdx * TILE_F;

    // ---- Weff recompute, ONCE per block (outside the rep loop).
    for (int i = t; i < 7 * 44; i += 256) {
        int j = i / 44, d = i - j * 44;
        float acc = 0.0f;
        if (d < 42) {
            acc = W[j * 111 + d];
            int r = d / 7, c = d - r * 7;
            const float* ws = W + j * 111 + 42;
            #pragma unroll
            for (int i4 = 0; i4 < 4; ++i4)          // 24 row windows
                if (c >= i4 && c <= i4 + 3) acc += ws[r * 4 + i4];
            #pragma unroll
            for (int i3 = 0; i3 < 3; ++i3)          // 21 col windows
                if (r >= i3 && r <= i3 + 3) acc += ws[24 + c * 3 + i3];
            #pragma unroll
            for (int off = 0; off < 3; ++off)       // 12 "diag" (full 4x4 bug)
                #pragma unroll
                for (int c4 = 0; c4 < 4; ++c4)
                    if (r >= 2 - off && r <= 5 - off && c >= c4 && c <= c4 + 3)
                        acc += ws[45 + off * 4 + c4];
        }
        wl[i] = acc;                                // feats 57..68: zero masks
    }
    __syncthreads();

    for (int rep = 0; rep < nrep; ++rep) {
        // ---- Async stage: 10 x b128 + 2 x b32 direct to LDS, all in flight.
        #pragma unroll
        for (int k = 0; k < 10; ++k) {
            __builtin_amdgcn_global_load_lds(
                (const __attribute__((address_space(1))) void*)(src + k * 256 + l * 4),
                (__attribute__((address_space(3))) void*)(tw + k * 256),
                16, 0, 0);
        }
        #pragma unroll
        for (int m = 0; m < 2; ++m) {
            __builtin_amdgcn_global_load_lds(
                (const __attribute__((address_space(1))) void*)(src + 2560 + m * 64 + l),
                (__attribute__((address_space(3))) void*)(tw + 2560 + m * 64),
                4, 0, 0);
        }
        __syncthreads();   // drains vmcnt: tile ready; also separates passes

        // ---- Compute: one row per thread.
        float x[44];
        const float* xr = tw + l * 42;
        #pragma unroll
        for (int d = 0; d < 42; ++d) x[d] = xr[d];
        x[42] = x[43] = 0.0f;

        float acc[7];
        #pragma unroll
        for (int j = 0; j < 7; ++j) acc[j] = b[j];

        const float4* wl4 = (const float4*)wl;
        #pragma unroll
        for (int dq = 0; dq < 11; ++dq) {
            #pragma unroll
            for (int j = 0; j < 7; ++j) {
                const float4 wv = wl4[j * 11 + dq];
                acc[j] = fmaf(x[dq * 4 + 0], wv.x, acc[j]);
                acc[j] = fmaf(x[dq * 4 + 1], wv.y, acc[j]);
                acc[j] = fmaf(x[dq * 4 + 2], wv.z, acc[j]);
                acc[j] = fmaf(x[dq * 4 + 3], wv.w, acc[j]);
            }
        }

        float* o = out + (tileIdx * 64 + l) * 7;
        #pragma unroll
        for (int j = 0; j < 7; ++j) o[j] = acc[j];
        __syncthreads();   // pass boundary: no staging/read overlap hazards
    }
}

extern "C" void kernel_launch(void* const* d_in, const int* in_sizes, int n_in,
                              void* d_out, int out_size, void* d_ws, size_t ws_size,
                              hipStream_t stream) {
    const float* gs = (const float*)d_in[0];   // [B, 42] f32
    const float* W  = (const float*)d_in[1];   // [7, 111] f32
    const float* b  = (const float*)d_in[2];   // [7] f32
    float* out = (float*)d_out;                // [B, 7] f32

    int B = in_sizes[0] / 42;                  // 524288
    int tiles = B / 64;                        // 8192 wave-tiles

    // nrep=4 inside ONE dispatch: T_pass = dispatch_dur/4 (from profile),
    // cross-check vs (bench - 117.5). FETCH_SIZE reveals L3-warm vs re-fetch.
    ddqn_fused<<<dim3(tiles / 4), dim3(256), 0, stream>>>(gs, W, b, out, 4);
}